// Round 7
// baseline (219.139 us; speedup 1.0000x reference)
//
#include <hip/hip_runtime.h>

// MambaSP round-6b: register-resident scan (compile fix of r6: update_dpp ctrl/rmask
// must be compile-time constants -> templated dppadd_).
// R4/R5 falsified launch-overhead, serial-length and TLP theories; the invariant suspect
// is the LDS pipe (1/CU, shared by 8 waves) and ds_read latency (~120cy) on the
// recurrence. This version removes LDS from the dataflow:
//   - scan-step broadcast via v_readlane (VALU) from per-lane preprocessed registers
//     (each wave redundantly preprocesses its chunk's 128 positions: 2 per lane)
//   - ud global round-trip eliminated (K3 recomputes preprocess bit-identically)
//   - n-reduction via DPP row_shr/row_bcast (rocPRIM wave64 pattern) + readlane(63)
//   - K1: zero LDS, zero barriers. K3: 1KB ys[] + one barrier.
// Structure unchanged: 8 dispatches, NC=32/CL=128, grid (32,32)x128thr.

constexpr int   Bsz = 32;
constexpr int   Lsz = 4096;
constexpr int   NC  = 32;          // chunks per sequence
constexpr int   CL  = 128;         // chunk length (L/NC)
constexpr float SRinv = 1.0f / 4096.0f;

__device__ __forceinline__ float sigmoidf_(float v) {
    return 1.0f / (1.0f + __expf(-v));
}
__device__ __forceinline__ float rl_(float v, int lane) {
    return __int_as_float(__builtin_amdgcn_readlane(__float_as_int(v), lane));
}
template <int CTRL, int RMASK>
__device__ __forceinline__ float dppadd_(float v) {
    int t = __builtin_amdgcn_update_dpp(0, __float_as_int(v), CTRL, RMASK, 0xF, true);
    return v + __int_as_float(t);
}
// full-wave (64-lane) f32 sum, result wave-uniform (readlane 63)
__device__ __forceinline__ float wave_sum_(float v) {
    v = dppadd_<0x111, 0xF>(v);   // row_shr:1
    v = dppadd_<0x112, 0xF>(v);   // row_shr:2
    v = dppadd_<0x114, 0xF>(v);   // row_shr:4
    v = dppadd_<0x118, 0xF>(v);   // row_shr:8  -> lane 15 of each row = row sum
    v = dppadd_<0x142, 0xA>(v);   // row_bcast:15 -> rows 1,3
    v = dppadd_<0x143, 0xC>(v);   // row_bcast:31 -> rows 2,3; lane 63 = total
    return rl_(v, 63);
}

struct PP { float u0, u1, d0, d1; };

// conv+silu+softplus for position p of chunk c (bit-identical in K1 and K3)
__device__ __forceinline__ PP prep_(const float* __restrict__ xin, int base, int c, int p,
                                    float wi0, float wi1,
                                    float cw0, float cw1, float cw2, float cw3,
                                    float cw4, float cw5, float cw6, float cw7,
                                    float cb0, float cb1, float wx0, float wx129,
                                    float wd0, float wd1, float bd0, float bd1)
{
    const int l = base + p;
    float x0, x1, x2, x3;
    if (c == 0 && p < 3) {            // left edge of the sequence: zero-pad
        x3 = xin[l];
        x2 = (p >= 1) ? xin[l - 1] : 0.0f;
        x1 = (p >= 2) ? xin[l - 2] : 0.0f;
        x0 = 0.0f;
    } else {
        x0 = xin[l - 3]; x1 = xin[l - 2]; x2 = xin[l - 1]; x3 = xin[l];
    }
    float v0 = wi0 * (x0 * cw0 + x1 * cw1 + x2 * cw2 + x3 * cw3) + cb0;
    float v1 = wi1 * (x0 * cw4 + x1 * cw5 + x2 * cw6 + x3 * cw7) + cb1;
    PP r;
    r.u0 = v0 * sigmoidf_(v0);
    r.u1 = v1 * sigmoidf_(v1);
    float dt = r.u0 * wx0 + r.u1 * wx129;
    float a0 = dt * wd0 + bd0, a1 = dt * wd1 + bd1;
    r.d0 = ((a0 > 20.0f) ? a0 : log1pf(__expf(a0))) * SRinv;
    r.d1 = ((a1 > 20.0f) ? a1 : log1pf(__expf(a1))) * SRinv;
    return r;
}

// ---------------- K1: preprocess (in regs) + per-chunk (P,S) ----------------
__global__ __launch_bounds__(128) void k_chunk_scan(
    const float* __restrict__ xin,
    const float* __restrict__ W_in, const float* __restrict__ conv_w,
    const float* __restrict__ conv_b, const float* __restrict__ W_x,
    const float* __restrict__ W_dt, const float* __restrict__ b_dt,
    const float* __restrict__ A_log,
    float* __restrict__ Pc, float* __restrict__ Sc)
{
    const int c = blockIdx.x, b = blockIdx.y, tid = threadIdx.x;
    const int e = tid >> 6, n = tid & 63;
    const int base = b * Lsz + c * CL;

    const float wi0 = W_in[0], wi1 = W_in[1];
    const float cb0 = conv_b[0], cb1 = conv_b[1];
    const float wx0 = W_x[0], wx129 = W_x[129];
    const float wd0 = W_dt[0], wd1 = W_dt[1], bd0 = b_dt[0], bd1 = b_dt[1];
    const float c0 = conv_w[0], c1 = conv_w[1], c2 = conv_w[2], c3 = conv_w[3];
    const float c4 = conv_w[4], c5 = conv_w[5], c6 = conv_w[6], c7 = conv_w[7];

    PP pa = prep_(xin, base, c, n,      wi0, wi1, c0,c1,c2,c3, c4,c5,c6,c7, cb0,cb1, wx0,wx129, wd0,wd1,bd0,bd1);
    PP pb = prep_(xin, base, c, n + 64, wi0, wi1, c0,c1,c2,c3, c4,c5,c6,c7, cb0,cb1, wx0,wx129, wd0,wd1,bd0,bd1);

    const float Aen = -__expf(A_log[e * 64 + n]);
    const float wb0 = W_x[1 + n], wb1 = W_x[129 + 1 + n];
    const float dsel_a = e ? pa.d1 : pa.d0;
    const float dsel_b = e ? pb.d1 : pb.d0;

    float P = 1.0f, S = 0.0f;
    #pragma unroll 16
    for (int t = 0; t < 64; ++t) {
        float su0 = rl_(pa.u0, t), su1 = rl_(pa.u1, t), sd = rl_(dsel_a, t);
        float ue = e ? su1 : su0;
        float Bn = su0 * wb0 + su1 * wb1;
        float dA = __expf(sd * Aen);
        S = dA * S + (sd * ue) * Bn;
        P *= dA;
    }
    #pragma unroll 16
    for (int t = 0; t < 64; ++t) {
        float su0 = rl_(pb.u0, t), su1 = rl_(pb.u1, t), sd = rl_(dsel_b, t);
        float ue = e ? su1 : su0;
        float Bn = su0 * wb0 + su1 * wb1;
        float dA = __expf(sd * Aen);
        S = dA * S + (sd * ue) * Bn;
        P *= dA;
    }
    const int idx = (b * NC + c) * 128 + tid;
    Pc[idx] = P;
    Sc[idx] = S;
}

// ---------------- K3: lookback + re-scan + DPP reduction + epilogue ----------------
__global__ __launch_bounds__(128) void k_output(
    const float* __restrict__ xin,
    const float* __restrict__ Pc, const float* __restrict__ Sc,
    const float* __restrict__ W_in, const float* __restrict__ conv_w,
    const float* __restrict__ conv_b, const float* __restrict__ W_x,
    const float* __restrict__ W_dt, const float* __restrict__ b_dt,
    const float* __restrict__ A_log, const float* __restrict__ D_skip,
    const float* __restrict__ W_out,
    float* __restrict__ out)
{
    const int c = blockIdx.x, b = blockIdx.y, tid = threadIdx.x;
    const int e = tid >> 6, n = tid & 63;
    const int base = b * Lsz + c * CL;
    __shared__ float ys[2 * CL];      // 1KB: per-(t,e) reduced scalars

    const float wi0 = W_in[0], wi1 = W_in[1];
    const float cb0 = conv_b[0], cb1 = conv_b[1];
    const float wx0 = W_x[0], wx129 = W_x[129];
    const float wd0 = W_dt[0], wd1 = W_dt[1], bd0 = b_dt[0], bd1 = b_dt[1];
    const float c0 = conv_w[0], c1 = conv_w[1], c2 = conv_w[2], c3 = conv_w[3];
    const float c4 = conv_w[4], c5 = conv_w[5], c6 = conv_w[6], c7 = conv_w[7];

    PP pa = prep_(xin, base, c, n,      wi0, wi1, c0,c1,c2,c3, c4,c5,c6,c7, cb0,cb1, wx0,wx129, wd0,wd1,bd0,bd1);
    PP pb = prep_(xin, base, c, n + 64, wi0, wi1, c0,c1,c2,c3, c4,c5,c6,c7, cb0,cb1, wx0,wx129, wd0,wd1,bd0,bd1);

    const float Aen = -__expf(A_log[e * 64 + n]);
    const float wb0 = W_x[1 + n],  wb1 = W_x[129 + 1 + n];
    const float wc0 = W_x[65 + n], wc1 = W_x[129 + 65 + n];
    const float De  = e ? D_skip[1] : D_skip[0];
    const float dsel_a = e ? pa.d1 : pa.d0;
    const float dsel_b = e ? pb.d1 : pb.d0;

    // parallel lookback: h_in = sum_{j<c} (prod_{j<k<c} P_k) S_j  (coalesced L2 reads)
    float h = 0.0f;
    if (c > 0) {
        const float* Pb = Pc + (size_t)b * NC * 128 + tid;
        const float* Sb = Sc + (size_t)b * NC * 128 + tid;
        float runS = 0.0f, runP = 1.0f;
        #pragma unroll 8
        for (int j = c - 1; j >= 0; --j) {
            float Sj = Sb[j * 128];
            float Pj = Pb[j * 128];
            runS = __fmaf_rn(runP, Sj, runS);
            runP *= Pj;
        }
        h = runS;
    }

    #pragma unroll 16
    for (int t = 0; t < 64; ++t) {
        float su0 = rl_(pa.u0, t), su1 = rl_(pa.u1, t), sd = rl_(dsel_a, t);
        float ue = e ? su1 : su0;
        float Bn = su0 * wb0 + su1 * wb1;
        float Cn = su0 * wc0 + su1 * wc1;
        float dA = __expf(sd * Aen);
        h = dA * h + (sd * ue) * Bn;
        float tot = wave_sum_(h * Cn);
        if (n == 0) ys[2 * t + e] = tot + ue * De;
    }
    #pragma unroll 16
    for (int t = 0; t < 64; ++t) {
        float su0 = rl_(pb.u0, t), su1 = rl_(pb.u1, t), sd = rl_(dsel_b, t);
        float ue = e ? su1 : su0;
        float Bn = su0 * wb0 + su1 * wb1;
        float Cn = su0 * wc0 + su1 * wc1;
        float dA = __expf(sd * Aen);
        h = dA * h + (sd * ue) * Bn;
        float tot = wave_sum_(h * Cn);
        if (n == 0) ys[2 * (t + 64) + e] = tot + ue * De;
    }
    __syncthreads();

    // epilogue: thread tid handles position tid
    {
        const float wz0 = W_in[2], wz1 = W_in[3];
        const float wo0 = W_out[0], wo1 = W_out[1];
        float xv = xin[base + tid];
        float y0 = ys[2 * tid], y1 = ys[2 * tid + 1];
        float z0 = xv * wz0, z1 = xv * wz1;
        out[base + tid] = y0 * (z0 * sigmoidf_(z0)) * wo0 +
                          y1 * (z1 * sigmoidf_(z1)) * wo1 + xv;
    }
}

extern "C" void kernel_launch(void* const* d_in, const int* in_sizes, int n_in,
                              void* d_out, int out_size, void* d_ws, size_t ws_size,
                              hipStream_t stream) {
    const float* x      = (const float*)d_in[0];
    const float* W_in   = (const float*)d_in[1];   // [4,1,4]
    const float* conv_w = (const float*)d_in[2];   // [4,2,4]
    const float* conv_b = (const float*)d_in[3];   // [4,2]
    const float* W_x    = (const float*)d_in[4];   // [4,2,129]
    const float* W_dt   = (const float*)d_in[5];   // [4,1,2]
    const float* b_dt   = (const float*)d_in[6];   // [4,2]
    const float* A_log  = (const float*)d_in[7];   // [4,2,64]
    const float* D_skip = (const float*)d_in[8];   // [4,2]
    const float* W_out  = (const float*)d_in[9];   // [4,2,1]
    float* out = (float*)d_out;

    float* ws   = (float*)d_ws;
    float* Pc   = ws;                                 // B*NC*128
    float* Sc   = Pc + (size_t)Bsz * NC * 128;
    float* buf0 = Sc + (size_t)Bsz * NC * 128;
    float* buf1 = buf0 + (size_t)Bsz * Lsz;

    const float* cur = x;
    for (int i = 0; i < 4; i++) {
        float* o = (i == 3) ? out : ((i & 1) ? buf1 : buf0);
        k_chunk_scan<<<dim3(NC, Bsz), 128, 0, stream>>>(
            cur, W_in + i * 4, conv_w + i * 8, conv_b + i * 2,
            W_x + i * 258, W_dt + i * 2, b_dt + i * 2, A_log + i * 128,
            Pc, Sc);
        k_output<<<dim3(NC, Bsz), 128, 0, stream>>>(
            cur, Pc, Sc, W_in + i * 4, conv_w + i * 8, conv_b + i * 2,
            W_x + i * 258, W_dt + i * 2, b_dt + i * 2, A_log + i * 128,
            D_skip + i * 2, W_out + i * 2, o);
        cur = o;
    }
}

// Round 8
// 166.812 us; speedup vs baseline: 1.3137x; 1.3137x over previous
//
#include <hip/hip_runtime.h>

// MambaSP round-8: packed-float2 (e0,e1) scan, 1 wave per chunk.
// Evidence: R5 (chain/TLP) neutral, R7 (2x instructions) +53us -> kernels are
// issue-throughput-bound. This version halves issued ops per unit work:
//   - both e-channels packed in float2 per thread -> v_pk_*_f32 dual f32
//   - 64-thread single-wave blocks (barriers ~free), CL=64/NC=64, grid 2048 = 8/CU
//   - K3 reads ud[base+t] as wave-uniform global b128 (no LDS staging)
//   - proven ps[] stride-65 reduce (T=32 -> 17KB LDS, 8 blocks/CU OK)
//   - packed lookback (float2 fma chains, coalesced dwordx2)
// Structure unchanged: 8 dispatches (K1 aggregates, K3 lookback+rescan+reduce).

constexpr int   Bsz = 32;
constexpr int   Lsz = 4096;
constexpr int   NC  = 64;          // chunks per sequence
constexpr int   CL  = 64;          // chunk length (L/NC)
constexpr float SRinv = 1.0f / 4096.0f;

typedef float fx2 __attribute__((ext_vector_type(2)));

__device__ __forceinline__ float sigmoidf_(float v) {
    return 1.0f / (1.0f + __expf(-v));
}

// ---------------- K1: preprocess + per-chunk packed (P,S) ----------------
__global__ __launch_bounds__(64) void k_chunk_scan(
    const float* __restrict__ xin,    // [B,L] layer input
    const float* __restrict__ W_in,   // [4]
    const float* __restrict__ conv_w, // [2,4]
    const float* __restrict__ conv_b, // [2]
    const float* __restrict__ W_x,    // [2,129]
    const float* __restrict__ W_dt,   // [2]
    const float* __restrict__ b_dt,   // [2]
    const float* __restrict__ A_log,  // [2,64]
    float4* __restrict__ ud,          // [B*L] {u0,u1,d0,d1}
    fx2* __restrict__ Pc,             // [B,NC,64] packed (e0,e1)
    fx2* __restrict__ Sc)             // [B,NC,64]
{
    const int c = blockIdx.x, b = blockIdx.y, n = threadIdx.x;
    __shared__ float  xs[CL + 3];
    __shared__ float4 s_ud[CL];
    const int base = b * Lsz + c * CL;

    xs[3 + n] = xin[base + n];
    if (n < 3) xs[n] = (c > 0) ? xin[base - 3 + n] : 0.0f;
    __syncthreads();

    // preprocess position n
    {
        float x0 = xs[n], x1 = xs[n + 1], x2 = xs[n + 2], x3 = xs[n + 3];
        float u[2];
        #pragma unroll
        for (int e = 0; e < 2; e++) {
            float v = W_in[e] * (x0 * conv_w[e * 4 + 0] + x1 * conv_w[e * 4 + 1] +
                                 x2 * conv_w[e * 4 + 2] + x3 * conv_w[e * 4 + 3]) +
                      conv_b[e];
            u[e] = v * sigmoidf_(v);   // silu
        }
        float dt = u[0] * W_x[0] + u[1] * W_x[129];
        float dl[2];
        #pragma unroll
        for (int e = 0; e < 2; e++) {
            float a = dt * W_dt[e] + b_dt[e];
            float sp = (a > 20.0f) ? a : log1pf(__expf(a));
            dl[e] = sp * SRinv;
        }
        float4 v4 = make_float4(u[0], u[1], dl[0], dl[1]);
        s_ud[n] = v4;
        ud[base + n] = v4;
    }
    __syncthreads();

    // packed chunk scan: thread n holds states (e=0,n) and (e=1,n)
    const fx2 A2 = { -__expf(A_log[n]), -__expf(A_log[64 + n]) };
    const float wb0 = W_x[1 + n], wb1 = W_x[129 + 1 + n];
    fx2 P = {1.0f, 1.0f}, S = {0.0f, 0.0f};
    #pragma unroll 8
    for (int l = 0; l < CL; l++) {
        float4 v = s_ud[l];
        float Bn = v.x * wb0 + v.y * wb1;
        fx2 u = {v.x, v.y};
        fx2 d = {v.z, v.w};
        fx2 darg = d * A2;
        fx2 dA = { __expf(darg.x), __expf(darg.y) };
        S = dA * S + (d * u) * Bn;
        P *= dA;
    }
    const int idx = (b * NC + c) * 64 + n;
    Pc[idx] = P;
    Sc[idx] = S;
}

// ---------------- K3: packed lookback + re-scan + reduce + epilogue ----------------
__global__ __launch_bounds__(64) void k_output(
    const float* __restrict__ xin,
    const float4* __restrict__ ud,
    const fx2* __restrict__ Pc,
    const fx2* __restrict__ Sc,
    const float* __restrict__ W_in,   // z weights at [2],[3]
    const float* __restrict__ W_x,
    const float* __restrict__ A_log,
    const float* __restrict__ D_skip, // [2]
    const float* __restrict__ W_out,  // [2]
    float* __restrict__ out)          // [B,L]
{
    const int c = blockIdx.x, b = blockIdx.y, n = threadIdx.x;
    constexpr int T = 32;             // positions per reduction tile
    __shared__ float ps[2 * T][65];   // rows (q*2+e), stride 65 (bank-safe)
    __shared__ float ys[2 * CL];
    const int base = b * Lsz + c * CL;

    const fx2 A2 = { -__expf(A_log[n]), -__expf(A_log[64 + n]) };
    const float wb0 = W_x[1 + n],  wb1 = W_x[129 + 1 + n];
    const float wc0 = W_x[65 + n], wc1 = W_x[129 + 65 + n];

    // packed parallel lookback: h_in = sum_{j<c} (prod_{j<k<c} P_k) S_j
    fx2 h = {0.0f, 0.0f};
    if (c > 0) {
        const fx2* Pb = Pc + (size_t)b * NC * 64 + n;
        const fx2* Sb = Sc + (size_t)b * NC * 64 + n;
        fx2 runS = {0.0f, 0.0f}, runP = {1.0f, 1.0f};
        #pragma unroll 8
        for (int j = c - 1; j >= 0; --j) {
            fx2 Sj = Sb[j * 64];
            fx2 Pj = Pb[j * 64];
            runS = runP * Sj + runS;
            runP *= Pj;
        }
        h = runS;
    }

    for (int tile = 0; tile < CL / T; ++tile) {
        #pragma unroll 8
        for (int q = 0; q < T; q++) {
            float4 v = ud[base + tile * T + q];   // wave-uniform b128 (L2)
            float Bn = v.x * wb0 + v.y * wb1;
            float Cn = v.x * wc0 + v.y * wc1;
            fx2 u = {v.x, v.y};
            fx2 d = {v.z, v.w};
            fx2 darg = d * A2;
            fx2 dA = { __expf(darg.x), __expf(darg.y) };
            h = dA * h + (d * u) * Bn;
            fx2 yc = h * Cn;
            ps[q * 2 + 0][n] = yc.x;
            ps[q * 2 + 1][n] = yc.y;
        }
        __syncthreads();
        // reduce: thread r sums row r (64 values), rows = T*2 = 64
        {
            const int r = n, q = r >> 1, re = r & 1;
            const int t = tile * T + q;
            const float* row = ps[r];
            float a0 = 0, a1 = 0, a2 = 0, a3 = 0;
            #pragma unroll
            for (int j = 0; j < 64; j += 4) {
                a0 += row[j]; a1 += row[j + 1]; a2 += row[j + 2]; a3 += row[j + 3];
            }
            float4 v = ud[base + t];
            float ue = re ? v.y : v.x;
            float De = re ? D_skip[1] : D_skip[0];
            ys[t * 2 + re] = (a0 + a1) + (a2 + a3) + ue * De;
        }
        __syncthreads();
    }

    // epilogue: thread n handles position n
    {
        const float wz0 = W_in[2], wz1 = W_in[3];
        const float wo0 = W_out[0], wo1 = W_out[1];
        float xv = xin[base + n];
        float y0 = ys[2 * n], y1 = ys[2 * n + 1];
        float z0 = xv * wz0, z1 = xv * wz1;
        out[base + n] = y0 * (z0 * sigmoidf_(z0)) * wo0 +
                        y1 * (z1 * sigmoidf_(z1)) * wo1 + xv;
    }
}

extern "C" void kernel_launch(void* const* d_in, const int* in_sizes, int n_in,
                              void* d_out, int out_size, void* d_ws, size_t ws_size,
                              hipStream_t stream) {
    const float* x      = (const float*)d_in[0];
    const float* W_in   = (const float*)d_in[1];   // [4,1,4]
    const float* conv_w = (const float*)d_in[2];   // [4,2,4]
    const float* conv_b = (const float*)d_in[3];   // [4,2]
    const float* W_x    = (const float*)d_in[4];   // [4,2,129]
    const float* W_dt   = (const float*)d_in[5];   // [4,1,2]
    const float* b_dt   = (const float*)d_in[6];   // [4,2]
    const float* A_log  = (const float*)d_in[7];   // [4,2,64]
    const float* D_skip = (const float*)d_in[8];   // [4,2]
    const float* W_out  = (const float*)d_in[9];   // [4,2,1]
    float* out = (float*)d_out;

    float* ws   = (float*)d_ws;
    float4* ud  = (float4*)ws;                        // B*L float4
    fx2* Pc     = (fx2*)(ws + (size_t)Bsz * Lsz * 4); // B*NC*64 fx2
    fx2* Sc     = Pc + (size_t)Bsz * NC * 64;
    float* buf0 = (float*)(Sc + (size_t)Bsz * NC * 64);
    float* buf1 = buf0 + (size_t)Bsz * Lsz;

    const float* cur = x;
    for (int i = 0; i < 4; i++) {
        float* o = (i == 3) ? out : ((i & 1) ? buf1 : buf0);
        k_chunk_scan<<<dim3(NC, Bsz), 64, 0, stream>>>(
            cur, W_in + i * 4, conv_w + i * 8, conv_b + i * 2,
            W_x + i * 258, W_dt + i * 2, b_dt + i * 2, A_log + i * 128,
            ud, Pc, Sc);
        k_output<<<dim3(NC, Bsz), 64, 0, stream>>>(
            cur, ud, Pc, Sc, W_in + i * 4, W_x + i * 258,
            A_log + i * 128, D_skip + i * 2, W_out + i * 2, o);
        cur = o;
    }
}